// Round 6
// baseline (56.190 us; speedup 1.0000x reference)
//
#include <hip/hip_runtime.h>
#include <math.h>

// (B,T,C)=(16,2048,1024), H=16, K=31, R=64, causal pad P=30.
// out[b,t,c] = sum_{j=0..30} w_rev[h(c),j] * x[b,t-j,c],  w_rev[j] = softmax(w)[30-j]
#define TPB  512
#define KW   31
#define HALO (KW - 1)          // 30
#define TT   8                 // outputs per thread
#define BT   128               // t-rows per block (16 subtiles x 8)
#define RQ   40                // staging quads (4 rows each -> 160 rows in LDS)
constexpr int B_ = 16, T_ = 2048, C_ = 1024, H_ = 16;
constexpr int C2 = C_ / 2;     // float2 pairs per t-row (512)
constexpr int PPH = 32;        // float2 pairs per head (R=64 channels)

__device__ inline float rfl(float v) {   // lane-uniform float -> SGPR
    return __builtin_bit_cast(float, __builtin_amdgcn_readfirstlane(__builtin_bit_cast(int, v)));
}

// Single fused kernel. Block = (head h, 128-row t-tile, batch b).
// Phase 1: issue async global_load_lds for 160 rows x 256 B (40 KB, linear dest).
// Phase 2: while DMA is in flight, compute softmax(w[h]) redundantly per thread
//          (block-uniform scalar loads + exp chain), push to SGPR via readfirstlane.
// Phase 3: barrier; accumulator-major compute from LDS (b64 reads, conflict-free
//          as measured round 5); float2 stores (exactly 134 MB write).
// TPB=512 @ 40KB LDS -> 8 waves x 4 blocks/CU = 100% occupancy cap (round 5: 50%).
__global__ __launch_bounds__(TPB, 8) void lconv_kernel(const float* __restrict__ x,
                                                       const float* __restrict__ w,
                                                       float* __restrict__ out) {
    __shared__ float smem[4 * RQ * 64];      // 160 rows * 64 floats = 40 KB
    const int h   = blockIdx.x;
    const int b   = blockIdx.z;
    const int t0b = blockIdx.y * BT;
    const int tid  = threadIdx.x;
    const int lane = tid & 63;
    const int wid  = tid >> 6;               // 0..7

    // ---- phase 1: staging. quad q = rows 4q..4q+3; lane l -> row 4q+(l>>4), chunk (l&15)
    const int qrow  = lane >> 4;
    const int chunk = lane & 15;
    const float* xh = x + (size_t)b * T_ * C_ + h * 64;   // head base
    #pragma unroll
    for (int q = wid; q < RQ; q += 8) {      // 5 issues per wave
        int t = t0b - HALO + 4 * q + qrow;
        t = min(max(t, 0), T_ - 1);          // clamp; y==0 halo re-zeroed below
        const float* gsrc = xh + (size_t)t * C_ + chunk * 4;
        __builtin_amdgcn_global_load_lds(
            (const __attribute__((address_space(1))) uint32_t*)gsrc,
            (__attribute__((address_space(3))) uint32_t*)(smem + q * 256),
            16, 0, 0);
    }

    // ---- phase 2: softmax(w[h]) under the DMA. Block-uniform -> s_load + uniform VALU.
    float wv[KW];
    {
        float v[KW];
        float m = -1e30f;
        #pragma unroll
        for (int k = 0; k < KW; ++k) { v[k] = w[h * KW + k]; m = fmaxf(m, v[k]); }
        float s = 0.f;
        #pragma unroll
        for (int k = 0; k < KW; ++k) { v[k] = __expf(v[k] - m); s += v[k]; }
        const float inv = 1.f / s;
        #pragma unroll
        for (int j = 0; j < KW; ++j) wv[j] = rfl(v[KW - 1 - j] * inv);  // reversed, to SGPR
    }

    __syncthreads();                          // drains vmcnt -> LDS stable
    if (blockIdx.y == 0) {                    // true zero-pad for t<0
        for (int k = tid; k < HALO * 64; k += TPB) smem[k] = 0.f;
        __syncthreads();
    }

    // ---- phase 3: compute
    const int pair = tid & 31;                // float2 pair within head
    const int sub  = tid >> 5;                // t-subtile 0..15

    float2 acc[TT];
    #pragma unroll
    for (int i = 0; i < TT; ++i) acc[i] = make_float2(0.f, 0.f);

    const float2* sm2 = (const float2*)smem;
    #pragma unroll
    for (int sr = 0; sr < TT + HALO; ++sr) {  // 38 rows per thread
        const float2 v = sm2[(size_t)(sub * TT + sr) * PPH + pair];
        const int ilo = (sr - HALO < 0) ? 0 : sr - HALO;
        const int ihi = (sr < TT - 1) ? sr : TT - 1;
        #pragma unroll
        for (int i = ilo; i <= ihi; ++i) {    // j = i + HALO - sr, static
            const float wj = wv[i + HALO - sr];
            acc[i].x = fmaf(wj, v.x, acc[i].x);
            acc[i].y = fmaf(wj, v.y, acc[i].y);
        }
    }

    float2* po = (float2*)out + ((size_t)b * T_ + t0b + sub * TT) * C2 + h * PPH + pair;
    #pragma unroll
    for (int i = 0; i < TT; ++i) po[(size_t)i * C2] = acc[i];
}

extern "C" void kernel_launch(void* const* d_in, const int* in_sizes, int n_in,
                              void* d_out, int out_size, void* d_ws, size_t ws_size,
                              hipStream_t stream) {
    const float* x = (const float*)d_in[0];
    const float* w = (const float*)d_in[1];
    float* out = (float*)d_out;

    dim3 grid(H_, T_ / BT, B_);   // (16, 16, 16) = 4096 blocks
    hipLaunchKernelGGL(lconv_kernel, grid, dim3(TPB), 0, stream, x, w, out);
}